// Round 11
// baseline (2250.356 us; speedup 1.0000x reference)
//
#include <hip/hip_runtime.h>
#include <cstddef>

// LSTM: x[64,512,512] f32, kernel[512,4096] f32, rec_kernel[1024,4096] f32,
// bias[4096] f32 -> h_last[64,1024] f32.
// R8 (resubmitted; round 10 was an infra failure — same error class hit the
// known-good R7 in round 8): RMW-free signaling + per-wave self-sync +
// drain overlap.
//  - Per-block sentinel: each wave vmcnt(0)-drains its h stores, then one LDS
//    fetch_add; the 4th wave stores the block's epoch to a private 128B line.
//    Replaces 64 serialized same-line MALL RMWs (R7's fetch_add tail) with
//    256 parallel plain stores to distinct lines.
//  - Consumer wave wv polls exactly the 16 block sentinels it consumes
//    (lanes 0-15, 1 line each, s_sleep backoff). No intra-block relay.
//  - Wave skew safety: barrier = per-instance rendezvous => sibling skew <= 1
//    interval => zsh parity-buffered. Cross-block WAR: triple-buffered h;
//    distance-2 transitivity (poll(t) => 16 blocks done t-1 => their unions
//    cover all 64 => all done t-2) => epoch-(t-3) reads complete before
//    buf[t mod 3] reuse. Double-buffer would NOT suffice; triple does.
//  - Drain overlap: next step's x-part MFMAs sit between h-store issue and
//    vmcnt(0), hiding the drain and publishing the sentinel earlier.

namespace {
constexpr int cB = 64;
constexpr int cT = 512;
constexpr int cD = 512;
constexpr int cU = 1024;
constexpr int cG = 4096;   // 4*U
constexpr int NBLK = 256;
constexpr int NT = 256;
}

typedef __attribute__((ext_vector_type(8))) short   short8;
typedef __attribute__((ext_vector_type(8))) __bf16  bf16x8;
typedef __attribute__((ext_vector_type(4))) float   f32x4;

__device__ inline short f2bf(float f) {
  unsigned u = __float_as_uint(f);
  u += 0x7fffu + ((u >> 16) & 1u);   // round-to-nearest-even
  return (short)(u >> 16);
}

__device__ inline f32x4 mfma16(short8 a, short8 b, f32x4 c) {
  return __builtin_amdgcn_mfma_f32_16x16x32_bf16(
      __builtin_bit_cast(bf16x8, a), __builtin_bit_cast(bf16x8, b), c, 0, 0, 0);
}

__device__ inline float sigm(float x) { return 1.0f / (1.0f + __expf(-x)); }
__device__ inline float tanh_(float x) {
  float a = fabsf(x);
  float e = __expf(-2.0f * a);
  float t = (1.0f - e) / (1.0f + e);
  return x < 0.0f ? -t : t;
}

__global__ __launch_bounds__(NT, 1) void lstm_persist(
    const float* __restrict__ x, const float* __restrict__ wk,
    const float* __restrict__ wr, const float* __restrict__ bias,
    float* __restrict__ out, short* __restrict__ xbf,
    short* hx, unsigned* sent, unsigned* flags) {
  const int tid  = threadIdx.x;
  const int wv   = tid >> 6;        // wave = K-slice owner (kc === wv mod 4)
  const int lane = tid & 63;
  const int n    = lane & 15;       // MFMA A row m / C col
  const int quad = lane >> 4;
  const int bid  = blockIdx.x;
  const int mt   = bid & 3;         // batch m-tile (16 rows each)
  const int cg   = bid >> 2;        // u-group 0..63 (16 u each)
  const int ub   = cg * 16;

  __shared__ float zsh[2][4 * 16 * 66]; // parity-buffered partial z planes
  __shared__ unsigned done;             // monotonic LDS vote counter

  if (tid == 0) done = 0u;

  // ---- phase 0: convert x to bf16 once (grid-stride) ----
  {
    const f32x4* xv = reinterpret_cast<const f32x4*>(x);
    short8* xo = reinterpret_cast<short8*>(xbf);
    const size_t nvec = (size_t)cB * cT * cD / 8;
    for (size_t i = (size_t)bid * NT + tid; i < nvec; i += (size_t)NBLK * NT) {
      f32x4 v0 = xv[2 * i];
      f32x4 v1 = xv[2 * i + 1];
      short8 s;
      s[0] = f2bf(v0[0]); s[1] = f2bf(v0[1]); s[2] = f2bf(v0[2]); s[3] = f2bf(v0[3]);
      s[4] = f2bf(v1[0]); s[5] = f2bf(v1[1]); s[6] = f2bf(v1[2]); s[7] = f2bf(v1[3]);
      xo[i] = s;
    }
  }

  // ---- time-invariant W fragments: Bf[i][g], kc = wv + 4*i, i=0..11 ----
  short8 Bf[12][4];
  #pragma unroll
  for (int i = 0; i < 12; ++i) {
    const int kc = wv + 4 * i;
    const int k0 = kc * 32 + quad * 8;
    #pragma unroll
    for (int g = 0; g < 4; ++g) {
      const int col = g * cU + ub + n;
      short8 b;
      #pragma unroll
      for (int j = 0; j < 8; ++j) {
        const int k = k0 + j;
        const float wgt = (k < cD) ? wk[(size_t)k * cG + col]
                                   : wr[(size_t)(k - cD) * cG + col];
        b[j] = f2bf(wgt);
      }
      Bf[i][g] = b;
    }
  }

  // ---- distributed epilogue mapping: thread -> (row, single u) ----
  const int erow = tid >> 4;        // 0..15
  const int eu   = tid & 15;        // 0..15
  const int hrow = mt * 16 + erow;
  const float bi  = bias[0 * cU + ub + eu];
  const float bff = bias[1 * cU + ub + eu];
  const float bc  = bias[2 * cU + ub + eu];
  const float bo  = bias[3 * cU + ub + eu];
  float cst = 0.0f;

  const int brow = mt * 16 + n;
  const short* xrow = xbf + (size_t)brow * cT * cD + quad * 8;

  // ---- initial full-grid barrier: xbf ready everywhere ----
  __builtin_amdgcn_fence(__ATOMIC_RELEASE, "agent");
  __syncthreads();
  if (tid == 0)
    __hip_atomic_store(flags + bid * 16, 1u, __ATOMIC_RELEASE,
                       __HIP_MEMORY_SCOPE_AGENT);
  if (wv == 0) {
    #pragma unroll
    for (int j = 0; j < 4; ++j) {
      const unsigned* fp = flags + (j * 64 + lane) * 16;
      while (__hip_atomic_load(fp, __ATOMIC_RELAXED,
                               __HIP_MEMORY_SCOPE_AGENT) < 1u) {}
    }
  }
  __syncthreads();
  __builtin_amdgcn_fence(__ATOMIC_ACQUIRE, "agent");

  const unsigned long long* hxu =
      reinterpret_cast<const unsigned long long*>(hx);
  // consumer h-load offset within a buffer (ull units), layout [cg'][mt][r][u']
  const size_t hoff = (size_t)(quad >> 1) * 256 + (size_t)mt * 64 +
                      (size_t)n * 4 + (size_t)(quad & 1) * 2;
  // producer sentinel line (128B each, one per block)
  unsigned* sentp = sent + (size_t)(cg * 4 + mt) * 32;
  // consumer poll lines: wave wv consumes blocks cg' = 2*(wv+4i)+b
  const unsigned* pollp = sent;     // dummy for lanes >= 16
  if (lane < 16) {
    const int cgp = 2 * (wv + 4 * (lane >> 1)) + (lane & 1);
    pollp = sent + (size_t)(cgp * 4 + mt) * 32;
  }

  // ---- prologue: x-part for t=0 ----
  f32x4 acc[4] = {{0,0,0,0},{0,0,0,0},{0,0,0,0},{0,0,0,0}};
  {
    const short* xr = xrow;
    #pragma unroll
    for (int i = 0; i < 4; ++i) {
      short8 af = *reinterpret_cast<const short8*>(xr + (wv + 4 * i) * 32);
      #pragma unroll
      for (int g = 0; g < 4; ++g) acc[g] = mfma16(af, Bf[i][g], acc[g]);
    }
  }

  int wb = 0, rb = 0;   // triple-buffer write/read indices

  for (int t = 0; t < cT; ++t) {
    if (t > 0) {
      // ---- per-wave poll: 16 block sentinels, 1 line per lane ----
      if (lane < 16) {
        const unsigned tgt = (unsigned)t;
        while (__hip_atomic_load(pollp, __ATOMIC_RELAXED,
                                 __HIP_MEMORY_SCOPE_AGENT) < tgt)
          __builtin_amdgcn_s_sleep(1);
      }
      asm volatile("" ::: "memory");   // no load hoisting above the wait

      // ---- h A-frags straight to registers (buffer rb) ----
      const unsigned long long* hb = hxu + (size_t)rb * 16384 + hoff;
      unsigned long long hv[16];
      #pragma unroll
      for (int i = 0; i < 8; ++i) {
        const int off = (wv + 4 * i) * 512;
        hv[2 * i]     = __hip_atomic_load(hb + off,     __ATOMIC_RELAXED,
                                          __HIP_MEMORY_SCOPE_AGENT);
        hv[2 * i + 1] = __hip_atomic_load(hb + off + 1, __ATOMIC_RELAXED,
                                          __HIP_MEMORY_SCOPE_AGENT);
      }
      #pragma unroll
      for (int i = 0; i < 8; ++i) {
        union { unsigned long long q[2]; short8 s; } u_;
        u_.q[0] = hv[2 * i]; u_.q[1] = hv[2 * i + 1];
        #pragma unroll
        for (int g = 0; g < 4; ++g)
          acc[g] = mfma16(u_.s, Bf[4 + i][g], acc[g]);
      }
    }

    // ---- per-wave partial z to zsh[par] plane wv ----
    const int par = t & 1;
    #pragma unroll
    for (int g = 0; g < 4; ++g)
      #pragma unroll
      for (int r = 0; r < 4; ++r)
        zsh[par][(wv * 16 + quad * 4 + r) * 66 + g * 16 + n] = acc[g][r];
    __syncthreads();   // per-instance rendezvous: siblings aligned here

    // ---- distributed epilogue: 1 u per thread; sum 4 wave-planes ----
    const float* zp = zsh[par];
    float z[4];
    #pragma unroll
    for (int g = 0; g < 4; ++g)
      z[g] = zp[(erow) * 66 + g * 16 + eu] +
             zp[(16 + erow) * 66 + g * 16 + eu] +
             zp[(32 + erow) * 66 + g * 16 + eu] +
             zp[(48 + erow) * 66 + g * 16 + eu];
    const float ig = sigm(z[0] + bi);
    const float fg = sigm(z[1] + bff);
    const float gg = tanh_(z[2] + bc);
    const float og = sigm(z[3] + bo);
    cst = fg * cst + ig * gg;
    const float h = og * tanh_(cst);

    if (t == cT - 1) {
      out[(size_t)hrow * cU + ub + eu] = h;
    } else {
      // issue contiguous 512B block publish (2B per thread)
      __hip_atomic_store(hx + (size_t)wb * 65536 +
                             (size_t)(cg * 4 + mt) * 256 + tid,
                         f2bf(h), __ATOMIC_RELAXED, __HIP_MEMORY_SCOPE_AGENT);

      // ---- x-part for t+1 overlaps the store drain ----
      #pragma unroll
      for (int g = 0; g < 4; ++g) acc[g] = f32x4{0, 0, 0, 0};
      {
        const short* xr = xrow + (size_t)(t + 1) * cD;
        #pragma unroll
        for (int i = 0; i < 4; ++i) {
          short8 af = *reinterpret_cast<const short8*>(xr + (wv + 4 * i) * 32);
          #pragma unroll
          for (int g = 0; g < 4; ++g) acc[g] = mfma16(af, Bf[i][g], acc[g]);
        }
      }

      // drain this wave's stores, then LDS vote; 4th wave stores sentinel
      asm volatile("s_waitcnt vmcnt(0)" ::: "memory");
      if (lane == 0) {
        const unsigned old = __hip_atomic_fetch_add(
            &done, 1u, __ATOMIC_ACQ_REL, __HIP_MEMORY_SCOPE_WORKGROUP);
        if ((old & 3u) == 3u)
          __hip_atomic_store(sentp, (old >> 2) + 1u, __ATOMIC_RELAXED,
                             __HIP_MEMORY_SCOPE_AGENT);
      }
      rb = wb;
      wb = (wb == 2) ? 0 : wb + 1;
    }
  }
}

extern "C" void kernel_launch(void* const* d_in, const int* in_sizes, int n_in,
                              void* d_out, int out_size, void* d_ws, size_t ws_size,
                              hipStream_t stream) {
  const float* x    = (const float*)d_in[0];
  const float* wk   = (const float*)d_in[1];
  const float* wr   = (const float*)d_in[2];
  const float* bias = (const float*)d_in[3];
  float* out = (float*)d_out;

  char* ws = (char*)d_ws;
  unsigned* flags = (unsigned*)ws;                 // 256 slots x 64B = 16 KB
  unsigned* sent  = (unsigned*)(ws + 16384);       // 256 blocks x 128B = 32 KB
  short* hx  = (short*)(ws + 49152);               // 3 x 128KB bf16 h buffers
  short* xbf = (short*)(ws + 49152 + 393216);      // x bf16, 32 MB

  // zero flags (startup barrier) + sentinels (epoch 0 < any target 1..511).
  hipMemsetAsync(ws, 0, 49152, stream);

  lstm_persist<<<dim3(NBLK), dim3(NT), 0, stream>>>(
      x, wk, wr, bias, out, xbf, hx, sent, flags);
}